// Round 4
// baseline (1334.747 us; speedup 1.0000x reference)
//
#include <hip/hip_runtime.h>
#include <stdint.h>

#define SLEN 100
#define NSEQ 4096
#define PRED 12

typedef unsigned short ushort_t;
typedef unsigned int uint_t;

#if __has_builtin(__builtin_amdgcn_rcpf)
#define RCP(x) __builtin_amdgcn_rcpf(x)
#else
#define RCP(x) (1.0f/(x))
#endif

__device__ __forceinline__ float bfu(ushort_t u){ return __uint_as_float(((uint_t)u)<<16); }
__device__ __forceinline__ float bflo(uint_t u){ return __uint_as_float(u<<16); }
__device__ __forceinline__ float bfhi(uint_t u){ return __uint_as_float(u & 0xffff0000u); }
__device__ __forceinline__ ushort_t f2bf(float f){
  uint_t u = __float_as_uint(f);
  u += 0x7fffu + ((u>>16)&1u);
  return (ushort_t)(u>>16);
}
__device__ __forceinline__ uint_t pk2(float a, float b){
  return (uint_t)f2bf(a) | ((uint_t)f2bf(b)<<16);
}
__device__ __forceinline__ float fsig(float x){ return RCP(1.f + __expf(-x)); }
__device__ __forceinline__ float ftanh(float x){ float e = __expf(x+x); return 1.f - 2.f*RCP(e+1.f); }

// ---------------- Encoder: bidirectional GRU over S=100 steps ----------------
__global__ __launch_bounds__(256, 2)
void k_encoder(const float* __restrict__ src,
               const float* __restrict__ WihF, const float* __restrict__ WhhF,
               const float* __restrict__ bihF, const float* __restrict__ bhhF,
               const float* __restrict__ WihB, const float* __restrict__ WhhB,
               const float* __restrict__ bihB, const float* __restrict__ bhhB,
               ushort_t* __restrict__ encO, float* __restrict__ hlast)
{
  __shared__ __align__(16) float Wrz[64*64*2];   // [k][j][{r,z}]
  __shared__ __align__(16) float Wn [64*64];     // [k][j]
  __shared__ __align__(16) float hpack[4*64*4];  // [wave][k][seq4]
  __shared__ __align__(16) float xbuf[4][12];

  const int t = threadIdx.x;
  const int dir = blockIdx.x >> 8;
  const int grp = blockIdx.x & 255;
  const float* Wih = dir ? WihB : WihF;
  const float* Whh = dir ? WhhB : WhhF;
  const float* bih = dir ? bihB : bihF;
  const float* bhh = dir ? bhhB : bhhF;

  for (int e = t; e < 12288; e += 256) {
    float v = Whh[e];
    int row = e >> 6, k = e & 63;
    int g = row >> 6, j = row & 63;
    if (g < 2) Wrz[(k*64+j)*2 + g] = v;
    else       Wn[k*64+j] = v;
  }
  const int w = t >> 6, lane = t & 63;
  const int n0 = grp*16 + w*4;

  float rw[3][3];
  #pragma unroll
  for (int g = 0; g < 3; ++g)
    #pragma unroll
    for (int i = 0; i < 3; ++i)
      rw[g][i] = Wih[(g*64 + lane)*3 + i];
  const float br  = bih[lane]     + bhh[lane];
  const float bz  = bih[64+lane]  + bhh[64+lane];
  const float bni = bih[128+lane];
  const float bnh = bhh[128+lane];

  float hreg[4] = {0.f,0.f,0.f,0.f};
  *(float4*)&hpack[(w*64+lane)*4] = make_float4(0.f,0.f,0.f,0.f);
  __syncthreads();

  for (int st = 0; st < SLEN; ++st) {
    const int sidx = dir ? (SLEN-1 - st) : st;
    if (lane < 12) {
      int q = lane/3, i = lane - q*3;
      int n = n0 + q;
      xbuf[w][lane] = src[(((n>>5)*SLEN + sidx)*96) + (n&31)*3 + i];
    }
    __syncthreads();

    float a_r[4], a_z[4], a_n[4], gn[4];
    #pragma unroll
    for (int q = 0; q < 4; ++q) {
      float x0 = xbuf[w][q*3+0], x1 = xbuf[w][q*3+1], x2 = xbuf[w][q*3+2];
      a_r[q] = br  + x0*rw[0][0] + x1*rw[0][1] + x2*rw[0][2];
      a_z[q] = bz  + x0*rw[1][0] + x1*rw[1][1] + x2*rw[1][2];
      gn[q]  = bni + x0*rw[2][0] + x1*rw[2][1] + x2*rw[2][2];
      a_n[q] = bnh;
    }
    #pragma unroll 4
    for (int k = 0; k < 64; ++k) {
      float2 wrz = *(const float2*)&Wrz[(k*64+lane)*2];
      float  wn  = Wn[k*64+lane];
      float4 h4  = *(const float4*)&hpack[(w*64+k)*4];   // broadcast read
      a_r[0] += h4.x*wrz.x; a_z[0] += h4.x*wrz.y; a_n[0] += h4.x*wn;
      a_r[1] += h4.y*wrz.x; a_z[1] += h4.y*wrz.y; a_n[1] += h4.y*wn;
      a_r[2] += h4.z*wrz.x; a_z[2] += h4.z*wrz.y; a_n[2] += h4.z*wn;
      a_r[3] += h4.w*wrz.x; a_z[3] += h4.w*wrz.y; a_n[3] += h4.w*wn;
    }
    float4 hnew;
    float* hn = (float*)&hnew;
    #pragma unroll
    for (int q = 0; q < 4; ++q) {
      float r  = fsig(a_r[q]);
      float z  = fsig(a_z[q]);
      float nn = ftanh(gn[q] + r*a_n[q]);
      float hv = nn + z*(hreg[q] - nn);
      hreg[q] = hv; hn[q] = hv;
      encO[((n0+q)*SLEN + sidx)*128 + dir*64 + lane] = f2bf(hv);
    }
    // Wave-synchronous store: all k-loop ds_reads of hpack[w][*] by this wave
    // precede this ds_write in program order; wave_barrier is a zero-cost
    // compiler fence preventing the store from being scheduled above them.
    __builtin_amdgcn_wave_barrier();
    *(float4*)&hpack[(w*64+lane)*4] = hnew;
  }
  #pragma unroll
  for (int q = 0; q < 4; ++q)
    hlast[(dir*NSEQ + n0+q)*64 + lane] = hreg[q];
}

// ---------------- h_dec0 = [hf|hb] @ e2d_W.T + e2d_b ----------------
__global__ __launch_bounds__(256)
void k_hdec0(const float* __restrict__ hlast, const float* __restrict__ e2dW,
             const float* __restrict__ e2db, float* __restrict__ h0g)
{
  const int t = threadIdx.x, w = t>>6, lane = t&63;
  const int n = blockIdx.x*4 + w;
  const float* hf = hlast + n*64;
  const float* hb = hlast + (NSEQ + n)*64;
  float a0 = e2db[lane], a1 = 0.f;
  #pragma unroll 4
  for (int k = 0; k < 64; k += 2) {
    a0 += hf[k]  *e2dW[lane*128 + k]      + hb[k]  *e2dW[lane*128 + 64 + k];
    a1 += hf[k+1]*e2dW[lane*128 + k + 1]  + hb[k+1]*e2dW[lane*128 + 65 + k];
  }
  h0g[n*64 + lane] = a0 + a1;
}

// ---------------- encWb = enc_out @ We.T + attn_b (step-invariant) ----------------
__global__ __launch_bounds__(512)
void k_encwb(const ushort_t* __restrict__ encO, const float* __restrict__ attnW,
             const float* __restrict__ attnb, ushort_t* __restrict__ encWbG)
{
  __shared__ __align__(16) uint_t encL[96*64];   // 96 rows x 128 bf16
  __shared__ __align__(16) float  WeT[128*64];   // [k][j]
  const int t = threadIdx.x;
  const int row0 = blockIdx.x * 96;
  const int nrows = (409600 - row0) < 96 ? (409600 - row0) : 96;
  const uint_t* srcp = (const uint_t*)(encO) + row0*64;
  for (int e = t; e < nrows*64; e += 512) encL[e] = srcp[e];
  for (int e = t; e < 8192; e += 512) {
    int j = e >> 7, k = e & 127;
    WeT[k*64 + j] = attnW[j*192 + 64 + k];
  }
  __syncthreads();
  const int w = t>>6, lane = t&63;
  const float ab = attnb[lane];
  for (int rr = 0; rr < 12; ++rr) {
    int row = w*12 + rr;
    if (row0 + row >= 409600) break;
    float a0 = ab, a1 = 0.f;
    #pragma unroll 8
    for (int k2 = 0; k2 < 64; ++k2) {
      uint_t u = encL[row*64 + k2];
      a0 += bflo(u)*WeT[(2*k2  )*64 + lane];
      a1 += bfhi(u)*WeT[(2*k2+1)*64 + lane];
    }
    encWbG[(row0+row)*64 + lane] = f2bf(a0 + a1);
  }
}

// ---------------- Decoder: 12 fused attention+GRU steps, 1 block = 1 sequence ----------------
__global__ __launch_bounds__(256, 2)
void k_decoder(const float* __restrict__ src,
               const ushort_t* __restrict__ encO, const ushort_t* __restrict__ encWbG,
               const float* __restrict__ h0g,
               const float* __restrict__ attnW, const float* __restrict__ attnv,
               const float* __restrict__ dWih, const float* __restrict__ dWhh,
               const float* __restrict__ dbih, const float* __restrict__ dbhh,
               const float* __restrict__ outWg, const float* __restrict__ outbg,
               float* __restrict__ out)
{
  __shared__ __align__(16) ushort_t encBT[128*104]; // enc transposed [k][s], pad 104
  __shared__ __align__(16) ushort_t encWbL[100*66]; // [s][j], pad 66
  __shared__ __align__(16) ushort_t WhT[64*64];     // attn hid-part [k][j]
  __shared__ __align__(16) ushort_t WihIs[3*192];   // dec input-weights [i][g]
  __shared__ __align__(16) float brz[128];
  __shared__ __align__(16) float bnn[128];
  __shared__ __align__(16) float vat[64];
  __shared__ __align__(16) float outWs[192];
  __shared__ __align__(16) float outbs[4];
  __shared__ __align__(16) float hbuf[64];
  __shared__ __align__(16) float hWb[64];
  __shared__ __align__(16) float score[104];
  __shared__ __align__(16) float ctx[128];
  __shared__ __align__(16) float gbuf[256];         // aliased: score-partials / gates
  __shared__ __align__(16) float inpb[4];

  const int t = threadIdx.x;
  const int n = blockIdx.x;

  // per-gate weight columns in registers: ctx-weights packed bf16, h-weights fp32
  uint_t wihc[64];
  float  whhf[64];
  if (t < 192) {
    const float* wr = dWih + t*131 + 3;
    #pragma unroll
    for (int kk = 0; kk < 64; ++kk) wihc[kk] = pk2(wr[2*kk], wr[2*kk+1]);
    const float* hr = dWhh + t*64;
    #pragma unroll
    for (int kk = 0; kk < 64; ++kk) whhf[kk] = hr[kk];
  }
  // LDS fills
  const ushort_t* eb = encO + n*12800;
  for (int e = t; e < 12800; e += 256) {
    int s = e >> 7, k = e & 127;
    encBT[k*104 + s] = eb[e];
  }
  // zero the s=100..103 padding of encBT: P4 reads it (times score==0, but
  // uninitialized LDS can hold Inf/NaN bf16 patterns and NaN*0 = NaN).
  for (int e = t; e < 512; e += 256) {
    int k = e >> 2, s = 100 + (e & 3);
    encBT[k*104 + s] = 0;
  }
  const ushort_t* ew = encWbG + n*6400;
  for (int e = t; e < 6400; e += 256) {
    int s = e >> 6, j = e & 63;
    encWbL[s*66 + j] = ew[e];
  }
  for (int e = t; e < 4096; e += 256) {
    int j = e >> 6, k = e & 63;
    WhT[k*64 + j] = f2bf(attnW[j*192 + k]);
  }
  if (t < 192) {
    WihIs[t]       = f2bf(dWih[t*131 + 0]);
    WihIs[192 + t] = f2bf(dWih[t*131 + 1]);
    WihIs[384 + t] = f2bf(dWih[t*131 + 2]);
    outWs[t] = outWg[t];
  }
  if (t < 128) brz[t] = dbih[t] + dbhh[t];
  if (t < 64) { bnn[t] = dbih[128+t]; bnn[64+t] = dbhh[128+t]; vat[t] = attnv[t]; hbuf[t] = h0g[n*64+t]; }
  if (t < 4)  outbs[t] = (t < 3) ? outbg[t] : 0.f;
  if (t < 3)  inpb[t] = src[((n>>5)*SLEN + (SLEN-1))*96 + (n&31)*3 + t];
  if (t >= 100 && t < 104) score[t] = 0.f;   // padding stays zero all steps
  __syncthreads();

  for (int st = 0; st < PRED; ++st) {
    // P1: hW = h @ Wh.T
    if (t < 64) {
      float a0 = 0.f, a1 = 0.f;
      #pragma unroll 8
      for (int k = 0; k < 64; k += 2) {
        a0 += hbuf[k]  *bfu(WhT[k*64 + t]);
        a1 += hbuf[k+1]*bfu(WhT[(k+1)*64 + t]);
      }
      hWb[t] = a0 + a1;
    }
    __syncthreads();
    // P2: score partials: tanh(hW + encWb) . v  (attn_b folded into encWb)
    if (t < 200) {
      int s = t % 100, jh = t / 100;
      const ushort_t* erow = &encWbL[s*66 + jh*32];
      float p = 0.f;
      #pragma unroll
      for (int j4 = 0; j4 < 8; ++j4) {
        float4 hw4 = *(const float4*)&hWb[jh*32 + j4*4];
        uint_t u0 = *(const uint_t*)&erow[j4*4];
        uint_t u1 = *(const uint_t*)&erow[j4*4 + 2];
        float4 vv  = *(const float4*)&vat[jh*32 + j4*4];
        p += ftanh(hw4.x + bflo(u0))*vv.x;
        p += ftanh(hw4.y + bfhi(u0))*vv.y;
        p += ftanh(hw4.z + bflo(u1))*vv.z;
        p += ftanh(hw4.w + bfhi(u1))*vv.w;
      }
      gbuf[jh*100 + s] = p;
    }
    __syncthreads();
    // P3: softmax over s (wave 0)
    if (t < 64) {
      float sA = gbuf[t] + gbuf[100+t];
      float sB = (t < 36) ? (gbuf[64+t] + gbuf[164+t]) : -1e30f;
      float m = fmaxf(sA, sB);
      #pragma unroll
      for (int o = 32; o > 0; o >>= 1) m = fmaxf(m, __shfl_xor(m, o, 64));
      float pA = __expf(sA - m);
      float pB = (t < 36) ? __expf(sB - m) : 0.f;
      float sm = pA + pB;
      #pragma unroll
      for (int o = 32; o > 0; o >>= 1) sm += __shfl_xor(sm, o, 64);
      float inv = RCP(sm);
      score[t] = pA * inv;
      if (t < 36) score[64+t] = pB * inv;
    }
    __syncthreads();
    // P4: context[k] = sum_s aw[s] * enc[s][k]
    if (t < 128) {
      const uint_t* rowp = (const uint_t*)&encBT[t*104];
      float a0 = 0.f, a1 = 0.f;
      #pragma unroll 4
      for (int s2 = 0; s2 < 52; ++s2) {
        uint_t u = rowp[s2];
        float2 sc = *(const float2*)&score[s2*2];
        a0 += bflo(u)*sc.x;
        a1 += bfhi(u)*sc.y;
      }
      ctx[t] = a0 + a1;
    }
    __syncthreads();
    // P5: GRU gates (thread t = gate row g)
    if (t < 192) {
      float ai0 = inpb[0]*bfu(WihIs[t]) + inpb[1]*bfu(WihIs[192+t]) + inpb[2]*bfu(WihIs[384+t]);
      float ai1 = 0.f;
      #pragma unroll
      for (int kk = 0; kk < 64; ++kk) {
        uint_t wv = wihc[kk];
        float2 c2 = *(const float2*)&ctx[2*kk];
        ai0 += c2.x*bflo(wv);
        ai1 += c2.y*bfhi(wv);
      }
      float ah = 0.f;
      #pragma unroll
      for (int kk = 0; kk < 64; ++kk) ah += hbuf[kk]*whhf[kk];   // hbuf broadcast
      float ai = ai0 + ai1;
      if (t < 128) {
        gbuf[t] = fsig(ai + ah + brz[t]);
      } else {
        int j = t - 128;
        gbuf[128+j] = ai + bnn[j];      // inn + bih_n
        gbuf[192+j] = ah + bnn[64+j];   // hn  + bhh_n
      }
    }
    __syncthreads();
    // P6: combine + prediction
    if (t < 64) {
      float r = gbuf[t], z = gbuf[64+t];
      float nn = ftanh(gbuf[128+t] + r*gbuf[192+t]);
      float hv = nn + z*(hbuf[t] - nn);
      hbuf[t] = hv;
      float p0 = hv*outWs[t], p1 = hv*outWs[64+t], p2 = hv*outWs[128+t];
      #pragma unroll
      for (int o = 32; o > 0; o >>= 1) {
        p0 += __shfl_xor(p0, o, 64);
        p1 += __shfl_xor(p1, o, 64);
        p2 += __shfl_xor(p2, o, 64);
      }
      if (t < 3) {
        float pv = (t==0) ? p0 : ((t==1) ? p1 : p2);
        pv += outbs[t];
        out[((n>>5)*PRED + st)*96 + (n&31)*3 + t] = pv;
        inpb[t] = pv;
      }
    }
    __syncthreads();
  }
}

extern "C" void kernel_launch(void* const* d_in, const int* in_sizes, int n_in,
                              void* d_out, int out_size, void* d_ws, size_t ws_size,
                              hipStream_t stream)
{
  const float* src   = (const float*)d_in[0];
  const float* WihF  = (const float*)d_in[1];
  const float* WhhF  = (const float*)d_in[2];
  const float* bihF  = (const float*)d_in[3];
  const float* bhhF  = (const float*)d_in[4];
  const float* WihB  = (const float*)d_in[5];
  const float* WhhB  = (const float*)d_in[6];
  const float* bihB  = (const float*)d_in[7];
  const float* bhhB  = (const float*)d_in[8];
  const float* attnW = (const float*)d_in[9];
  const float* attnb = (const float*)d_in[10];
  const float* attnv = (const float*)d_in[11];
  const float* e2dW  = (const float*)d_in[12];
  const float* e2db  = (const float*)d_in[13];
  const float* dWih  = (const float*)d_in[14];
  const float* dWhh  = (const float*)d_in[15];
  const float* dbih  = (const float*)d_in[16];
  const float* dbhh  = (const float*)d_in[17];
  const float* outW  = (const float*)d_in[18];
  const float* outb  = (const float*)d_in[19];

  char* w = (char*)d_ws;
  ushort_t* encO   = (ushort_t*)w;                         // 104,857,600 B
  ushort_t* encWbG = (ushort_t*)(w + 104857600);           //  52,428,800 B
  float*    hlast  = (float*)   (w + 157286400);           //   2,097,152 B
  float*    h0g    = (float*)   (w + 159383552);           //   1,048,576 B
  float* out = (float*)d_out;

  hipLaunchKernelGGL(k_encoder, dim3(512), dim3(256), 0, stream,
                     src, WihF, WhhF, bihF, bhhF, WihB, WhhB, bihB, bhhB, encO, hlast);
  hipLaunchKernelGGL(k_hdec0, dim3(1024), dim3(256), 0, stream, hlast, e2dW, e2db, h0g);
  hipLaunchKernelGGL(k_encwb, dim3(4267), dim3(512), 0, stream, encO, attnW, attnb, encWbG);
  hipLaunchKernelGGL(k_decoder, dim3(4096), dim3(256), 0, stream,
                     src, encO, encWbG, h0g, attnW, attnv, dWih, dWhh, dbih, dbhh, outW, outb, out);
}